// Round 2
// baseline (1062.005 us; speedup 1.0000x reference)
//
#include <hip/hip_runtime.h>
#include <hip/hip_bf16.h>
#include <stdint.h>

#define BQ   32768
#define DD   1024
#define NHH  8
#define HH   128
#define EPSF 1e-6f
#define CAPF 15.0f

typedef unsigned short u16;
typedef short bf16x8 __attribute__((ext_vector_type(8)));
typedef float f32x4  __attribute__((ext_vector_type(4)));

__device__ __forceinline__ float bf2f(u16 v) {
  union { float f; unsigned u; } t; t.u = ((unsigned)v) << 16; return t.f;
}
__device__ __forceinline__ u16 f2bf(float f) {
  union { float f; unsigned u; } t; t.f = f;
  unsigned r = t.u + 0x7fffu + ((t.u >> 16) & 1u);
  return (u16)(r >> 16);
}

// async global->LDS, 16B per lane; LDS dest is wave-uniform base + lane*16
#define GLDS16(g, l) \
  __builtin_amdgcn_global_load_lds((const __attribute__((address_space(1))) unsigned int*)(g), \
                                   (__attribute__((address_space(3))) unsigned int*)(l), 16, 0, 0)

// ---------------------------------------------------------------------------
// 256x256 tile bf16 GEMM, C = A @ Bt^T (A:[M,K], Bt:[N,K] bf16), BK=64.
// 8 waves (2M x 4N), per-wave 128x64 output. Double-buffered LDS, 4 phases
// per K-tile: {ds_read quadrant | stage next-tile halves | s_barrier |
// setprio(1) 16xMFMA setprio(0) | s_barrier}; ONE vmcnt(0) per K-tile at the
// boundary (raw s_barrier everywhere in the loop -- no __syncthreads drain).
// LDS XOR involution (granule ^= row&7) on write-source and read, as verified
// in the previous passing kernel. XCD-chunked block swizzle (512 works).
// EPI 1: SiLU(x+bias)->bf16   EPI 2: gating + per-head LN   EPI 3: fp32
// ---------------------------------------------------------------------------
template <int EPI>
__global__ __launch_bounds__(512, 2)
void gemm256(const u16* __restrict__ A, const u16* __restrict__ Bt,
             int M, int N, int K,
             const float* __restrict__ bias,
             u16* __restrict__ obf,
             const float* __restrict__ cin, const float* __restrict__ nin,
             const float* __restrict__ gI, const float* __restrict__ gF,
             const float* __restrict__ gO,
             const float* __restrict__ gnw, const float* __restrict__ gnb,
             float* __restrict__ cout, float* __restrict__ nout,
             float* __restrict__ of32)
{
  __shared__ __align__(16) u16 As[2][256 * 64];   // 64 KiB
  __shared__ __align__(16) u16 Bs[2][256 * 64];   // 64 KiB
  __shared__ float redS[2][2][256];               // [partial][head][row]
  __shared__ float redQ[2][2][256];
  __shared__ float sgI[2][256], sgF[2][256], sgO[2][256];

  const int t = threadIdx.x;
  const int w = t >> 6;          // wave 0..7
  const int l = t & 63;

  // XCD-aware chunked swizzle: grid (4,128) -> 512 works, %8==0 -> bijective.
  // Within a 64-work XCD chunk, runs of 4 share the A-panel; B (2 MiB) L2-fits.
  const int orig = blockIdx.y * 4 + blockIdx.x;
  const int work = ((orig & 7) << 6) | (orig >> 3);
  const int m0 = (work >> 2) * 256;
  const int n0 = (work & 3) * 256;

  const int wm = w & 1, wn = w >> 1;   // 2M x 4N wave grid
  const int q = l >> 4, lc = l & 15;

  // staging: one issue = 512 thr x 16B = 64 rows of 128B. wave w owns rows
  // w*8..w*8+7 of each 64-row block; lane: row l>>3, granule l&7.
  // Source granule pre-swizzled by (row&7) so linear GLDS dest + XOR read
  // form the verified involution.
  const int srow = (w << 3) + (l >> 3);
  const int sgn  = ((l & 7) ^ (l >> 3)) << 3;
  const u16* gA = A  + (size_t)(m0 + srow) * K + sgn;
  const u16* gB = Bt + (size_t)(n0 + srow) * K + sgn;

  f32x4 acc[8][4];
#pragma unroll
  for (int i = 0; i < 8; ++i)
#pragma unroll
    for (int j = 0; j < 4; ++j)
      acc[i][j] = (f32x4){0.f, 0.f, 0.f, 0.f};

  const int axor  = (lc & 7) << 3;          // read-side XOR (elems)
  const int abase = (wm * 128 + lc) * 64;   // A-frag row base (elems)
  const int bbase = (wn * 64  + lc) * 64;   // B-frag row base

  bf16x8 af[4][2];   // current mh-half A-frags
  bf16x8 bq[4][2];   // all B-frags of the tile
  const int NT = K >> 6;    // 16

  // ---- prologue: stage K-tile 0 into buffer 0 (8 loads), drain, barrier
#pragma unroll
  for (int blk = 0; blk < 4; ++blk) {
    GLDS16(gA + (size_t)(blk * 64) * K, &As[0][(blk * 64 + (w << 3)) * 64]);
    GLDS16(gB + (size_t)(blk * 64) * K, &Bs[0][(blk * 64 + (w << 3)) * 64]);
  }
  asm volatile("s_waitcnt vmcnt(0)" ::: "memory");
  __builtin_amdgcn_s_barrier();

  for (int tk = 0; tk < NT; ++tk) {
    const int cb = tk & 1, nb = cb ^ 1;
    const size_t kn = (size_t)(tk + 1) << 6;
    const bool pf = (tk + 1 < NT);

    // ======== phase 0: read A0-3 + B0-1; stage A-blk0, A-blk1, B-blk0 ======
#pragma unroll
    for (int i = 0; i < 4; ++i)
#pragma unroll
      for (int kk = 0; kk < 2; ++kk)
        af[i][kk] = *(const bf16x8*)&As[cb][abase + i * 1024 + (((kk << 5) | (q << 3)) ^ axor)];
#pragma unroll
    for (int j = 0; j < 2; ++j)
#pragma unroll
      for (int kk = 0; kk < 2; ++kk)
        bq[j][kk] = *(const bf16x8*)&Bs[cb][bbase + j * 1024 + (((kk << 5) | (q << 3)) ^ axor)];
    if (pf) {
      GLDS16(gA + kn,                     &As[nb][(0 * 64 + (w << 3)) * 64]);
      GLDS16(gA + (size_t)64 * K + kn,    &As[nb][(1 * 64 + (w << 3)) * 64]);
      GLDS16(gB + kn,                     &Bs[nb][(0 * 64 + (w << 3)) * 64]);
    }
    __builtin_amdgcn_s_barrier();
    __builtin_amdgcn_s_setprio(1);
#pragma unroll
    for (int i = 0; i < 4; ++i)
#pragma unroll
      for (int j = 0; j < 2; ++j)
#pragma unroll
        for (int kk = 0; kk < 2; ++kk)
          acc[i][j] = __builtin_amdgcn_mfma_f32_16x16x32_bf16(af[i][kk], bq[j][kk], acc[i][j], 0, 0, 0);
    __builtin_amdgcn_s_setprio(0);
    __builtin_amdgcn_s_barrier();

    // ======== phase 1: read B2-3; stage A-blk2, A-blk3, B-blk1 =============
#pragma unroll
    for (int j = 0; j < 2; ++j)
#pragma unroll
      for (int kk = 0; kk < 2; ++kk)
        bq[2 + j][kk] = *(const bf16x8*)&Bs[cb][bbase + (2 + j) * 1024 + (((kk << 5) | (q << 3)) ^ axor)];
    if (pf) {
      GLDS16(gA + (size_t)128 * K + kn,   &As[nb][(2 * 64 + (w << 3)) * 64]);
      GLDS16(gA + (size_t)192 * K + kn,   &As[nb][(3 * 64 + (w << 3)) * 64]);
      GLDS16(gB + (size_t)64 * K + kn,    &Bs[nb][(1 * 64 + (w << 3)) * 64]);
    }
    __builtin_amdgcn_s_barrier();
    __builtin_amdgcn_s_setprio(1);
#pragma unroll
    for (int i = 0; i < 4; ++i)
#pragma unroll
      for (int j = 0; j < 2; ++j)
#pragma unroll
        for (int kk = 0; kk < 2; ++kk)
          acc[i][2 + j] = __builtin_amdgcn_mfma_f32_16x16x32_bf16(af[i][kk], bq[2 + j][kk], acc[i][2 + j], 0, 0, 0);
    __builtin_amdgcn_s_setprio(0);
    __builtin_amdgcn_s_barrier();

    // ======== phase 2: read A4-7 (overwrite af); stage B-blk2, B-blk3 ======
#pragma unroll
    for (int i = 0; i < 4; ++i)
#pragma unroll
      for (int kk = 0; kk < 2; ++kk)
        af[i][kk] = *(const bf16x8*)&As[cb][abase + (4 + i) * 1024 + (((kk << 5) | (q << 3)) ^ axor)];
    if (pf) {
      GLDS16(gB + (size_t)128 * K + kn,   &Bs[nb][(2 * 64 + (w << 3)) * 64]);
      GLDS16(gB + (size_t)192 * K + kn,   &Bs[nb][(3 * 64 + (w << 3)) * 64]);
    }
    __builtin_amdgcn_s_barrier();
    __builtin_amdgcn_s_setprio(1);
#pragma unroll
    for (int i = 0; i < 4; ++i)
#pragma unroll
      for (int j = 0; j < 2; ++j)
#pragma unroll
        for (int kk = 0; kk < 2; ++kk)
          acc[4 + i][j] = __builtin_amdgcn_mfma_f32_16x16x32_bf16(af[i][kk], bq[j][kk], acc[4 + i][j], 0, 0, 0);
    __builtin_amdgcn_s_setprio(0);
    __builtin_amdgcn_s_barrier();

    // ======== phase 3: no reads/stages; mfma; boundary vmcnt + barrier =====
    __builtin_amdgcn_s_setprio(1);
#pragma unroll
    for (int i = 0; i < 4; ++i)
#pragma unroll
      for (int j = 0; j < 2; ++j)
#pragma unroll
        for (int kk = 0; kk < 2; ++kk)
          acc[4 + i][2 + j] = __builtin_amdgcn_mfma_f32_16x16x32_bf16(af[i][kk], bq[2 + j][kk], acc[4 + i][2 + j], 0, 0, 0);
    __builtin_amdgcn_s_setprio(0);
    asm volatile("s_waitcnt vmcnt(0)" ::: "memory");   // next tile fully landed
    __builtin_amdgcn_s_barrier();
  }

  // C/D layout per 16x16 frag: col = base + lc, row = base + q*4 + r
  if constexpr (EPI == 1) {
#pragma unroll
    for (int i = 0; i < 8; ++i)
#pragma unroll
      for (int r = 0; r < 4; ++r) {
        size_t row = (size_t)(m0 + wm * 128 + i * 16 + q * 4 + r);
#pragma unroll
        for (int j = 0; j < 4; ++j) {
          int col = n0 + wn * 64 + j * 16 + lc;
          float v = acc[i][j][r] + bias[col];
          float s = v / (1.f + expf(-v));       // SiLU
          obf[row * (size_t)N + col] = f2bf(s);
        }
      }
  }

  if constexpr (EPI == 2) {
    const int hb = n0 >> 7;                     // global head base (2 heads/block)
    const int hd = wn >> 1, pi = wn & 1;        // wave's head (0/1) + partial id
    if (t < 256) {
      int rr = m0 + t;
      sgI[0][t] = gI[(size_t)rr * NHH + hb];     sgI[1][t] = gI[(size_t)rr * NHH + hb + 1];
      sgF[0][t] = gF[(size_t)rr * NHH + hb];     sgF[1][t] = gF[(size_t)rr * NHH + hb + 1];
      sgO[0][t] = gO[(size_t)rr * NHH + hb];     sgO[1][t] = gO[(size_t)rr * NHH + hb + 1];
    }
    __syncthreads();
#pragma unroll
    for (int i = 0; i < 8; ++i)
#pragma unroll
      for (int r = 0; r < 4; ++r) {
        int rloc = wm * 128 + i * 16 + q * 4 + r;
        size_t grow = (size_t)(m0 + rloc) * (size_t)N;
        float fg = sgF[hd][rloc], ig = sgI[hd][rloc], og = sgO[hd][rloc];
        float s = 0.f, ss = 0.f;
#pragma unroll
        for (int j = 0; j < 4; ++j) {
          int col = n0 + wn * 64 + j * 16 + lc;
          float z  = acc[i][j][r];
          float cv = fg * cin[grow + col] + ig * z;
          float nv = fg * nin[grow + col] + ig;
          cout[grow + col] = cv;
          nout[grow + col] = nv;
          float h = og * cv / (nv + EPSF);
          acc[i][j][r] = h;
          s += h; ss += h * h;
        }
#pragma unroll
        for (int mk = 1; mk < 16; mk <<= 1) {
          s  += __shfl_xor(s,  mk);
          ss += __shfl_xor(ss, mk);
        }
        if (lc == 0) { redS[pi][hd][rloc] = s; redQ[pi][hd][rloc] = ss; }
      }
    __syncthreads();
#pragma unroll
    for (int i = 0; i < 8; ++i)
#pragma unroll
      for (int r = 0; r < 4; ++r) {
        int rloc = wm * 128 + i * 16 + q * 4 + r;
        float s  = redS[0][hd][rloc] + redS[1][hd][rloc];
        float ss = redQ[0][hd][rloc] + redQ[1][hd][rloc];
        float mu  = s * (1.f / 128.f);
        float var = ss * (1.f / 128.f) - mu * mu;
        float rs  = rsqrtf(var + EPSF);
        size_t grow = (size_t)(m0 + rloc) * (size_t)N;
#pragma unroll
        for (int j = 0; j < 4; ++j) {
          int col = n0 + wn * 64 + j * 16 + lc;
          float hn = (acc[i][j][r] - mu) * rs * gnw[col] + gnb[col];
          obf[grow + col] = f2bf(hn);
        }
      }
  }

  if constexpr (EPI == 3) {
#pragma unroll
    for (int i = 0; i < 8; ++i)
#pragma unroll
      for (int r = 0; r < 4; ++r) {
        size_t row = (size_t)(m0 + wm * 128 + i * 16 + q * 4 + r);
#pragma unroll
        for (int j = 0; j < 4; ++j) {
          int col = n0 + wn * 64 + j * 16 + lc;
          of32[row * (size_t)N + col] = acc[i][j][r];
        }
      }
  }
}

// ---------------------------------------------------------------------------
// Gates: one wave per batch row. i/f from x_conv, o from x; softcap + stable
// exp gating. Writes i_g/f_g/o_g to ws, m_new to d_out.
// ---------------------------------------------------------------------------
__global__ __launch_bounds__(256)
void gates_k(const u16* __restrict__ xbf, const u16* __restrict__ xcbf,
             const u16* __restrict__ wi, const u16* __restrict__ wf,
             const u16* __restrict__ wo,
             const float* __restrict__ ib, const float* __restrict__ fb,
             const float* __restrict__ ob, const float* __restrict__ min_,
             float* __restrict__ gI, float* __restrict__ gF,
             float* __restrict__ gO, float* __restrict__ mout)
{
  const int w = threadIdx.x >> 6, l = threadIdx.x & 63;
  const int row = blockIdx.x * 4 + w;
  const u16* xr  = xbf  + (size_t)row * DD;
  const u16* xcr = xcbf + (size_t)row * DD;
  bf16x8 xa = *(const bf16x8*)(xr + l * 8);
  bf16x8 xb = *(const bf16x8*)(xr + 512 + l * 8);
  bf16x8 ca = *(const bf16x8*)(xcr + l * 8);
  bf16x8 cb = *(const bf16x8*)(xcr + 512 + l * 8);
  float xf[16], cf[16];
#pragma unroll
  for (int j = 0; j < 8; ++j) {
    xf[j] = bf2f((u16)xa[j]); xf[8 + j] = bf2f((u16)xb[j]);
    cf[j] = bf2f((u16)ca[j]); cf[8 + j] = bf2f((u16)cb[j]);
  }
#pragma unroll
  for (int h = 0; h < NHH; ++h) {
    const u16* wip = wi + h * DD;
    const u16* wfp = wf + h * DD;
    const u16* wop = wo + h * DD;
    bf16x8 wia = *(const bf16x8*)(wip + l * 8), wib = *(const bf16x8*)(wip + 512 + l * 8);
    bf16x8 wfa = *(const bf16x8*)(wfp + l * 8), wfb = *(const bf16x8*)(wfp + 512 + l * 8);
    bf16x8 woa = *(const bf16x8*)(wop + l * 8), wob = *(const bf16x8*)(wop + 512 + l * 8);
    float si = 0.f, sf = 0.f, so = 0.f;
#pragma unroll
    for (int j = 0; j < 8; ++j) {
      si += cf[j] * bf2f((u16)wia[j]) + cf[8 + j] * bf2f((u16)wib[j]);
      sf += cf[j] * bf2f((u16)wfa[j]) + cf[8 + j] * bf2f((u16)wfb[j]);
      so += xf[j] * bf2f((u16)woa[j]) + xf[8 + j] * bf2f((u16)wob[j]);
    }
#pragma unroll
    for (int mk = 1; mk < 64; mk <<= 1) {
      si += __shfl_xor(si, mk);
      sf += __shfl_xor(sf, mk);
      so += __shfl_xor(so, mk);
    }
    if (l == 0) {
      float it = CAPF * tanhf((si + ib[h]) / CAPF);
      float ft = CAPF * tanhf((sf + fb[h]) / CAPF);
      float ot = CAPF * tanhf((so + ob[h]) / CAPF);
      float flog = -log1pf(expf(-ft));            // log(sigmoid(f_t))
      float mo = min_[(size_t)row * NHH + h];
      float mn = fmaxf(flog + mo, it);
      size_t o = (size_t)row * NHH + h;
      gI[o] = expf(it - mn);
      gF[o] = expf(flog + mo - mn);
      gO[o] = 1.f / (1.f + expf(-ot));
      mout[o] = mn;
    }
  }
}

// ---------------------------------------------------------------------------
__global__ __launch_bounds__(256)
void cvt_f2b(const float* __restrict__ in, u16* __restrict__ out, int n4) {
  int i = blockIdx.x * 256 + threadIdx.x;
  if (i >= n4) return;
  float4 v = ((const float4*)in)[i];
  ushort4 o;
  o.x = f2bf(v.x); o.y = f2bf(v.y); o.z = f2bf(v.z); o.w = f2bf(v.w);
  ((ushort4*)out)[i] = o;
}

// w1[o,i] = conv_w[o, i, K-1]  (K=4), coalesced float4 gather
__global__ __launch_bounds__(256)
void cvt_conv(const float* __restrict__ cw, u16* __restrict__ w1) {
  int e = blockIdx.x * 256 + threadIdx.x;   // e < DD*DD
  float4 v = ((const float4*)cw)[e];
  w1[e] = f2bf(v.w);
}

// ---------------------------------------------------------------------------
extern "C" void kernel_launch(void* const* d_in, const int* in_sizes, int n_in,
                              void* d_out, int out_size, void* d_ws, size_t ws_size,
                              hipStream_t stream) {
  const float* x_in   = (const float*)d_in[0];
  const float* cst_in = (const float*)d_in[1];
  const float* nst_in = (const float*)d_in[2];
  const float* mst_in = (const float*)d_in[3];
  const float* conv_w = (const float*)d_in[4];
  const float* conv_b = (const float*)d_in[5];
  const float* z_w    = (const float*)d_in[6];
  const float* i_w    = (const float*)d_in[7];
  const float* i_b    = (const float*)d_in[8];
  const float* f_w    = (const float*)d_in[9];
  const float* f_b    = (const float*)d_in[10];
  const float* o_w    = (const float*)d_in[11];
  const float* o_b    = (const float*)d_in[12];
  const float* gn_w   = (const float*)d_in[13];
  const float* gn_b   = (const float*)d_in[14];
  const float* out_w  = (const float*)d_in[15];

  char* ws = (char*)d_ws;
  u16* x_bf  = (u16*)(ws);                     // 64 MiB
  u16* xc_bf = (u16*)(ws + 67108864);          // 64 MiB (reused as h_bf)
  u16* w1_bf = (u16*)(ws + 134217728);         // 2 MiB
  u16* zw_bf = (u16*)(ws + 136314880);         // 2 MiB
  u16* ow_bf = (u16*)(ws + 138412032);         // 2 MiB
  u16* wi_bf = (u16*)(ws + 140509184);         // 16 KiB
  u16* wf_bf = (u16*)(ws + 140525568);
  u16* wo_bf = (u16*)(ws + 140541952);
  float* gIv = (float*)(ws + 140558336);       // 1 MiB each
  float* gFv = (float*)(ws + 141606912);
  float* gOv = (float*)(ws + 142655488);       // end ~143.7 MB

  float* outp  = (float*)d_out;
  float* c_out = outp + (size_t)33554432;
  float* n_out = outp + (size_t)67108864;
  float* m_out = outp + (size_t)100663296;

  // 1) conversions
  cvt_f2b<<<dim3((BQ * DD / 4) / 256), 256, 0, stream>>>(x_in, x_bf, BQ * DD / 4);
  cvt_conv<<<dim3((DD * DD) / 256), 256, 0, stream>>>(conv_w, w1_bf);
  cvt_f2b<<<dim3((DD * DD / 4) / 256), 256, 0, stream>>>(z_w, zw_bf, DD * DD / 4);
  cvt_f2b<<<dim3((DD * DD / 4) / 256), 256, 0, stream>>>(out_w, ow_bf, DD * DD / 4);
  cvt_f2b<<<dim3((NHH * DD / 4 + 255) / 256), 256, 0, stream>>>(i_w, wi_bf, NHH * DD / 4);
  cvt_f2b<<<dim3((NHH * DD / 4 + 255) / 256), 256, 0, stream>>>(f_w, wf_bf, NHH * DD / 4);
  cvt_f2b<<<dim3((NHH * DD / 4 + 255) / 256), 256, 0, stream>>>(o_w, wo_bf, NHH * DD / 4);

  dim3 gg(DD / 256, BQ / 256);   // (4, 128) = 512 blocks, 512 threads

  // 2) x_conv = SiLU(x @ W1^T + conv_b)
  gemm256<1><<<gg, 512, 0, stream>>>(x_bf, w1_bf, BQ, DD, DD, conv_b, xc_bf,
                                     nullptr, nullptr, nullptr, nullptr, nullptr,
                                     nullptr, nullptr, nullptr, nullptr, nullptr);
  // 3) gates
  gates_k<<<dim3(BQ / 4), 256, 0, stream>>>(x_bf, xc_bf, wi_bf, wf_bf, wo_bf,
                                            i_b, f_b, o_b, mst_in, gIv, gFv, gOv, m_out);
  // 4) z GEMM + gating + per-head LN -> c_new, n_new, h_bf (reuses xc_bf buf)
  gemm256<2><<<gg, 512, 0, stream>>>(x_bf, zw_bf, BQ, DD, DD, nullptr, xc_bf,
                                     cst_in, nst_in, gIv, gFv, gOv, gn_w, gn_b,
                                     c_out, n_out, nullptr);
  // 5) out = h_norm @ out_w^T
  gemm256<3><<<gg, 512, 0, stream>>>(xc_bf, ow_bf, BQ, DD, DD, nullptr, nullptr,
                                     nullptr, nullptr, nullptr, nullptr, nullptr,
                                     nullptr, nullptr, nullptr, nullptr, outp);
}